// Round 11
// baseline (945.620 us; speedup 1.0000x reference)
//
#include <hip/hip_runtime.h>
#include <hip/hip_cooperative_groups.h>
#include <stdint.h>

namespace cg = cooperative_groups;

// GCN x2 layers x2 branches, N=50000, E=800000, C=64 — single cooperative
// persistent kernel. Phases separated by grid.sync():
//   P0 zero cnt | P1 histogram + per-edge rank | P2a/b/c 3-phase scan + dinv
//   P3 atomic-free CSR fill + layer-1 MFMA matmuls (interleaved per block)
//   P4 agg1 (both branches, interleaved f16 table) | P5 layer-2 MFMA matmuls
//   P6 agg2 + fused Wf dot | P7 per-graph pool + bias
// Tables are branch-interleaved f16 [node][128] (256 B/row, one uint32/lane).

typedef _Float16 f16;
typedef _Float16 f16x2 __attribute__((ext_vector_type(2)));
typedef _Float16 f16x8 __attribute__((ext_vector_type(8)));
typedef float f32x4 __attribute__((ext_vector_type(4)));

struct Args {
    const int* esrc; const int* edst;
    const float* x; const float* xsc;
    const float *W1, *b1, *W2, *b2, *We, *be;
    const float *W1s, *b1s, *W2s, *b2s, *Wes, *bes;
    const float *Wf, *bf;
    const int* batch;
    int* cnt; int* rank_; int* offs; int* bsums; int* elist;
    float* dinv; float* dot;
    f16 *A, *S, *H;
    float* out;
    int nN, nE, nG;
};

__device__ inline int lower_bound_d(const int* __restrict__ b, int n, int g) {
    int lo = 0, hi = n;
    while (lo < hi) { int m = (lo + hi) >> 1; if (b[m] < g) lo = m + 1; else hi = m; }
    return lo;
}

// 16x16x32 f16 layouts: A[row=l&15][k=(l>>4)*8+j]; B[k=(l>>4)*8+j][col=l&15];
// D[row=(l>>4)*4+j][col=l&15]  (m89-verified). Out pitch fixed at 128 f16.
template <bool F16IN, bool HASC>
__device__ void mm_dev(const void* __restrict__ Xv,
                       const float* __restrict__ Wa, const float* __restrict__ Wc,
                       const float* __restrict__ dinv,
                       f16* __restrict__ Oa, f16* __restrict__ Oc,
                       int n, int xP, int wid, int nwaves, int lane) {
    const int col = lane & 15, kgrp = lane >> 4;
    f16x8 wa[4][2], wc[4][2];
#pragma unroll
    for (int ct = 0; ct < 4; ++ct)
#pragma unroll
        for (int kk = 0; kk < 2; ++kk)
#pragma unroll
            for (int j = 0; j < 8; ++j) {
                int widx = (kk * 32 + kgrp * 8 + j) * 64 + ct * 16 + col;
                wa[ct][kk][j] = (f16)Wa[widx];
                if (HASC) wc[ct][kk][j] = (f16)Wc[widx];
            }
    const int ntiles = (n + 15) >> 4;
    for (int t = wid; t < ntiles; t += nwaves) {
        int arow = t * 16 + col;
        if (arow >= n) arow = n - 1;
        f16x8 af[2];
#pragma unroll
        for (int kk = 0; kk < 2; ++kk) {
            if (F16IN) {
                af[kk] = *(const f16x8*)((const f16*)Xv + (size_t)arow * xP + kk * 32 + kgrp * 8);
            } else {
                const float4* px = (const float4*)((const float*)Xv + (size_t)arow * xP + kk * 32 + kgrp * 8);
                float4 u0 = px[0], u1 = px[1];
                af[kk][0] = (f16)u0.x; af[kk][1] = (f16)u0.y;
                af[kk][2] = (f16)u0.z; af[kk][3] = (f16)u0.w;
                af[kk][4] = (f16)u1.x; af[kk][5] = (f16)u1.y;
                af[kk][6] = (f16)u1.z; af[kk][7] = (f16)u1.w;
            }
        }
        f32x4 acca[4], accc[4];
#pragma unroll
        for (int ct = 0; ct < 4; ++ct) {
            acca[ct] = (f32x4)(0.0f);
            if (HASC) accc[ct] = (f32x4)(0.0f);
        }
#pragma unroll
        for (int ct = 0; ct < 4; ++ct)
#pragma unroll
            for (int kk = 0; kk < 2; ++kk) {
                acca[ct] = __builtin_amdgcn_mfma_f32_16x16x32_f16(af[kk], wa[ct][kk], acca[ct], 0, 0, 0);
                if (HASC) accc[ct] = __builtin_amdgcn_mfma_f32_16x16x32_f16(af[kk], wc[ct][kk], accc[ct], 0, 0, 0);
            }
        int rbase = t * 16 + kgrp * 4;
#pragma unroll
        for (int j = 0; j < 4; ++j) {
            int row = rbase + j;
            if (row < n) {
                float d = dinv[row];
#pragma unroll
                for (int ct = 0; ct < 4; ++ct) {
                    Oa[(size_t)row * 128 + ct * 16 + col] = (f16)(d * acca[ct][j]);
                    if (HASC) Oc[(size_t)row * 128 + ct * 16 + col] = (f16)(accc[ct][j]);
                }
            }
        }
    }
}

__global__ __launch_bounds__(256, 4) void fused_k(Args a) {
    cg::grid_group grid = cg::this_grid();
    const int tid = threadIdx.x;
    const int lane = tid & 63;
    const int gtid = blockIdx.x * 256 + tid;
    const int gstride = gridDim.x * 256;
    const int wid = blockIdx.x * 4 + (tid >> 6);
    const int nwaves = gridDim.x * 4;

    // ---- P0: zero degree counters ----
    for (int i = gtid; i < a.nN; i += gstride) a.cnt[i] = 0;
    grid.sync();

    // ---- P1: degree histogram + per-edge rank (coalesced rank store) ----
    for (int e = gtid; e < a.nE; e += gstride)
        a.rank_[e] = atomicAdd(&a.cnt[a.edst[e]], 1);
    grid.sync();

    // ---- P2a: per-block chunk scan + dinv ----
    const int C = (a.nN + gridDim.x - 1) / gridDim.x;
    if (tid < 64) {
        int base = blockIdx.x * C;
        int carry = 0;
        for (int s0 = 0; s0 < C; s0 += 64) {
            int idx = s0 + tid;
            int i = base + idx;
            bool ok = (idx < C) && (i < a.nN);
            int v = ok ? a.cnt[i] : 0;
            if (ok) a.dinv[i] = 1.0f / sqrtf(1.0f + (float)v);
            int s = v;
#pragma unroll
            for (int off = 1; off < 64; off <<= 1) { int t = __shfl_up(s, off); if (lane >= off) s += t; }
            if (ok) a.offs[i] = carry + s - v;
            carry += __shfl(s, 63);
        }
        if (tid == 0) a.bsums[blockIdx.x] = carry;
    }
    grid.sync();

    // ---- P2b: exclusive scan of block sums (block 0, wave 0) ----
    if (blockIdx.x == 0 && tid < 64) {
        int carry = 0;
        for (int b0 = 0; b0 < (int)gridDim.x; b0 += 64) {
            int i = b0 + tid;
            int v = (i < (int)gridDim.x) ? a.bsums[i] : 0;
            int s = v;
#pragma unroll
            for (int off = 1; off < 64; off <<= 1) { int t = __shfl_up(s, off); if (lane >= off) s += t; }
            if (i < (int)gridDim.x) a.bsums[i] = carry + s - v;
            carry += __shfl(s, 63);
        }
    }
    grid.sync();

    // ---- P2c: add block offsets ----
    {
        int boff = a.bsums[blockIdx.x];
        for (int j = tid; j < C; j += 256) {
            int i = blockIdx.x * C + j;
            if (i < a.nN) a.offs[i] += boff;
        }
        if (gtid == 0) a.offs[a.nN] = a.nE;
    }
    grid.sync();

    // ---- P3: atomic-free CSR fill, then layer-1 matmuls (same phase) ----
    for (int e = gtid; e < a.nE; e += gstride)
        a.elist[a.offs[a.edst[e]] + a.rank_[e]] = a.esrc[e];
    mm_dev<false, true>(a.x,   a.W1,  a.We,  a.dinv, a.A,      a.S,      a.nN, 64, wid, nwaves, lane);
    mm_dev<false, true>(a.xsc, a.W1s, a.Wes, a.dinv, a.A + 64, a.S + 64, a.nN, 64, wid, nwaves, lane);
    grid.sync();

    // ---- P4: layer-1 agg, both branches over interleaved table ----
    {
        const uint32_t* Aw = (const uint32_t*)a.A;
        const uint32_t* Sw = (const uint32_t*)a.S;
        uint32_t* Hw = (uint32_t*)a.H;
        int br = lane >> 5;
        int ch0 = (lane & 31) * 2;
        float bb0 = br ? a.b1s[ch0] : a.b1[ch0];
        float bb1 = br ? a.b1s[ch0 + 1] : a.b1[ch0 + 1];
        float bs0 = br ? a.bes[ch0] : a.be[ch0];
        float bs1 = br ? a.bes[ch0 + 1] : a.be[ch0 + 1];
        for (int node = wid; node < a.nN; node += nwaves) {
            int e0 = a.offs[node], e1 = a.offs[node + 1];
            f16x2 sv = __builtin_bit_cast(f16x2, Aw[(size_t)node * 64 + lane]);
            float acc0 = (float)sv.x, acc1 = (float)sv.y;
            int e = e0;
            for (; e + 7 < e1; e += 8) {
                int s0 = a.elist[e],     s1 = a.elist[e + 1], s2 = a.elist[e + 2], s3 = a.elist[e + 3];
                int s4 = a.elist[e + 4], s5 = a.elist[e + 5], s6 = a.elist[e + 6], s7 = a.elist[e + 7];
                f16x2 v0 = __builtin_bit_cast(f16x2, Aw[(size_t)s0 * 64 + lane]);
                f16x2 v1 = __builtin_bit_cast(f16x2, Aw[(size_t)s1 * 64 + lane]);
                f16x2 v2 = __builtin_bit_cast(f16x2, Aw[(size_t)s2 * 64 + lane]);
                f16x2 v3 = __builtin_bit_cast(f16x2, Aw[(size_t)s3 * 64 + lane]);
                f16x2 v4 = __builtin_bit_cast(f16x2, Aw[(size_t)s4 * 64 + lane]);
                f16x2 v5 = __builtin_bit_cast(f16x2, Aw[(size_t)s5 * 64 + lane]);
                f16x2 v6 = __builtin_bit_cast(f16x2, Aw[(size_t)s6 * 64 + lane]);
                f16x2 v7 = __builtin_bit_cast(f16x2, Aw[(size_t)s7 * 64 + lane]);
                acc0 += (((float)v0.x + (float)v1.x) + ((float)v2.x + (float)v3.x)) +
                        (((float)v4.x + (float)v5.x) + ((float)v6.x + (float)v7.x));
                acc1 += (((float)v0.y + (float)v1.y) + ((float)v2.y + (float)v3.y)) +
                        (((float)v4.y + (float)v5.y) + ((float)v6.y + (float)v7.y));
            }
            for (; e < e1; ++e) {
                f16x2 v = __builtin_bit_cast(f16x2, Aw[(size_t)a.elist[e] * 64 + lane]);
                acc0 += (float)v.x; acc1 += (float)v.y;
            }
            float d = a.dinv[node];
            float g0 = fmaxf(d * acc0 + bb0, 0.0f);
            float g1 = fmaxf(d * acc1 + bb1, 0.0f);
            f16x2 skv = __builtin_bit_cast(f16x2, Sw[(size_t)node * 64 + lane]);
            g0 += fmaxf((float)skv.x + bs0, 0.0f);
            g1 += fmaxf((float)skv.y + bs1, 0.0f);
            f16x2 o; o.x = (f16)g0; o.y = (f16)g1;
            Hw[(size_t)node * 64 + lane] = __builtin_bit_cast(uint32_t, o);
        }
    }
    grid.sync();

    // ---- P5: layer-2 matmuls (f16 interleaved in/out) ----
    mm_dev<true, false>(a.H,      a.W2,  nullptr, a.dinv, a.A,      nullptr, a.nN, 128, wid, nwaves, lane);
    mm_dev<true, false>(a.H + 64, a.W2s, nullptr, a.dinv, a.A + 64, nullptr, a.nN, 128, wid, nwaves, lane);
    grid.sync();

    // ---- P6: layer-2 agg + fused Wf dot ----
    {
        const uint32_t* Aw = (const uint32_t*)a.A;
        const uint32_t* Hw = (const uint32_t*)a.H;
        int br = lane >> 5;
        int ch0 = (lane & 31) * 2;
        float bb0 = br ? a.b2s[ch0] : a.b2[ch0];
        float bb1 = br ? a.b2s[ch0 + 1] : a.b2[ch0 + 1];
        float wf0 = a.Wf[ch0], wf1 = a.Wf[ch0 + 1];
        for (int node = wid; node < a.nN; node += nwaves) {
            int e0 = a.offs[node], e1 = a.offs[node + 1];
            f16x2 sv = __builtin_bit_cast(f16x2, Aw[(size_t)node * 64 + lane]);
            float acc0 = (float)sv.x, acc1 = (float)sv.y;
            int e = e0;
            for (; e + 7 < e1; e += 8) {
                int s0 = a.elist[e],     s1 = a.elist[e + 1], s2 = a.elist[e + 2], s3 = a.elist[e + 3];
                int s4 = a.elist[e + 4], s5 = a.elist[e + 5], s6 = a.elist[e + 6], s7 = a.elist[e + 7];
                f16x2 v0 = __builtin_bit_cast(f16x2, Aw[(size_t)s0 * 64 + lane]);
                f16x2 v1 = __builtin_bit_cast(f16x2, Aw[(size_t)s1 * 64 + lane]);
                f16x2 v2 = __builtin_bit_cast(f16x2, Aw[(size_t)s2 * 64 + lane]);
                f16x2 v3 = __builtin_bit_cast(f16x2, Aw[(size_t)s3 * 64 + lane]);
                f16x2 v4 = __builtin_bit_cast(f16x2, Aw[(size_t)s4 * 64 + lane]);
                f16x2 v5 = __builtin_bit_cast(f16x2, Aw[(size_t)s5 * 64 + lane]);
                f16x2 v6 = __builtin_bit_cast(f16x2, Aw[(size_t)s6 * 64 + lane]);
                f16x2 v7 = __builtin_bit_cast(f16x2, Aw[(size_t)s7 * 64 + lane]);
                acc0 += (((float)v0.x + (float)v1.x) + ((float)v2.x + (float)v3.x)) +
                        (((float)v4.x + (float)v5.x) + ((float)v6.x + (float)v7.x));
                acc1 += (((float)v0.y + (float)v1.y) + ((float)v2.y + (float)v3.y)) +
                        (((float)v4.y + (float)v5.y) + ((float)v6.y + (float)v7.y));
            }
            for (; e < e1; ++e) {
                f16x2 v = __builtin_bit_cast(f16x2, Aw[(size_t)a.elist[e] * 64 + lane]);
                acc0 += (float)v.x; acc1 += (float)v.y;
            }
            float d = a.dinv[node];
            f16x2 hv = __builtin_bit_cast(f16x2, Hw[(size_t)node * 64 + lane]);
            float h0 = fmaxf(d * acc0 + bb0, 0.0f) + (float)hv.x;
            float h1 = fmaxf(d * acc1 + bb1, 0.0f) + (float)hv.y;
            float c = h0 * wf0 + h1 * wf1;
#pragma unroll
            for (int off = 32; off > 0; off >>= 1) c += __shfl_down(c, off);
            if (lane == 0) a.dot[node] = c;
        }
    }
    grid.sync();

    // ---- P7: per-graph mean pool + bias (batch sorted) ----
    if ((int)blockIdx.x < a.nG) {
        int g = blockIdx.x;
        int start = lower_bound_d(a.batch, a.nN, g);
        int end   = lower_bound_d(a.batch, a.nN, g + 1);
        float acc = 0.0f;
        for (int i = start + tid; i < end; i += 256) acc += a.dot[i];
#pragma unroll
        for (int off = 32; off > 0; off >>= 1) acc += __shfl_down(acc, off);
        __shared__ float part[4];
        if (lane == 0) part[tid >> 6] = acc;
        __syncthreads();
        if (tid == 0) {
            float s = part[0] + part[1] + part[2] + part[3];
            float c = fmaxf((float)(end - start), 1.0f);
            a.out[g] = s / c + a.bf[0];
        }
    }
}

static inline char* alignp(char* p, uintptr_t al) {
    return (char*)(((uintptr_t)p + al - 1) & ~(al - 1));
}

extern "C" void kernel_launch(void* const* d_in, const int* in_sizes, int n_in,
                              void* d_out, int out_size, void* d_ws, size_t ws_size,
                              hipStream_t stream) {
    const int nN = in_sizes[0] / 64;   // 50000
    const int nE = in_sizes[16] / 2;   // 800000
    const int nG = out_size;           // 64
    const int* ei = (const int*)d_in[16];

    // ---- workspace (64B-aligned chunks) ----
    char* p = (char*)d_ws;
    int* cnt    = (int*)p;   p = alignp(p + (size_t)nN * sizeof(int), 64);
    int* rank_  = (int*)p;   p = alignp(p + (size_t)nE * sizeof(int), 64);
    int* offs   = (int*)p;   p = alignp(p + (size_t)(nN + 1) * sizeof(int), 64);
    int* bsums  = (int*)p;   p = alignp(p + 1024 * sizeof(int), 64);
    int* elist  = (int*)p;   p = alignp(p + (size_t)nE * sizeof(int), 64);
    float* dinv = (float*)p; p = alignp(p + (size_t)nN * sizeof(float), 64);
    float* dot  = (float*)p; p = alignp(p + (size_t)nN * sizeof(float), 64);
    f16* A = (f16*)p;        p = alignp(p + (size_t)nN * 128 * sizeof(f16), 64);
    f16* S = (f16*)p;        p = alignp(p + (size_t)nN * 128 * sizeof(f16), 64);
    f16* H = (f16*)p;        p = alignp(p + (size_t)nN * 128 * sizeof(f16), 64);

    Args a;
    a.esrc = ei; a.edst = ei + nE;
    a.x   = (const float*)d_in[0];  a.xsc = (const float*)d_in[1];
    a.W1  = (const float*)d_in[2];  a.b1  = (const float*)d_in[3];
    a.W2  = (const float*)d_in[4];  a.b2  = (const float*)d_in[5];
    a.We  = (const float*)d_in[6];  a.be  = (const float*)d_in[7];
    a.W1s = (const float*)d_in[8];  a.b1s = (const float*)d_in[9];
    a.W2s = (const float*)d_in[10]; a.b2s = (const float*)d_in[11];
    a.Wes = (const float*)d_in[12]; a.bes = (const float*)d_in[13];
    a.Wf  = (const float*)d_in[14]; a.bf  = (const float*)d_in[15];
    a.batch = (const int*)d_in[17];
    a.cnt = cnt; a.rank_ = rank_; a.offs = offs; a.bsums = bsums; a.elist = elist;
    a.dinv = dinv; a.dot = dot;
    a.A = A; a.S = S; a.H = H;
    a.out = (float*)d_out;
    a.nN = nN; a.nE = nE; a.nG = nG;

    // Co-resident grid: __launch_bounds__(256,4) guarantees >= 4 blocks/CU.
    int maxB = 4;
    hipOccupancyMaxActiveBlocksPerMultiprocessor(&maxB, fused_k, 256, 0);
    int nBlk = maxB * 256;           // 256 CUs on MI355X
    if (nBlk > 1024) nBlk = 1024;    // bsums capacity
    if (nBlk < 64) nBlk = 64;        // pool needs >= nG blocks

    void* params[] = { (void*)&a };
    hipLaunchCooperativeKernel(fused_k, dim3(nBlk), dim3(256), params, 0, stream);
}

// Round 12
// 280.503 us; speedup vs baseline: 3.3712x; 3.3712x over previous
//
#include <hip/hip_runtime.h>
#include <stdint.h>

// GCN x2 layers x2 branches, N=50000, E=800000, C=64.
// Round-8 proven structure + atomic-free CSR fill via rank capture.
// Branch-interleaved f16 tables [node][128] (256 B/row); gathers read one
// uint32/lane covering both branches. MFMA 16x16x32 f16 matmuls (W in VGPRs).

typedef _Float16 f16;
typedef _Float16 f16x2 __attribute__((ext_vector_type(2)));
typedef _Float16 f16x8 __attribute__((ext_vector_type(8)));
typedef float f32x4 __attribute__((ext_vector_type(4)));

// ---- degree histogram + per-edge rank capture ----
__global__ void deg_rank_k(const int* __restrict__ dst, int nE,
                           int* __restrict__ cnt, int* __restrict__ rank_) {
    int i = blockIdx.x * blockDim.x + threadIdx.x;
    if (i < nE) rank_[i] = atomicAdd(&cnt[dst[i]], 1);
}

// ---- scanA: per-block (1024 elems) exclusive scan + dinv ----
__global__ __launch_bounds__(256) void scanA_k(const int* __restrict__ cnt, int n,
                                               int* __restrict__ offs, int* __restrict__ bsums,
                                               float* __restrict__ dinv) {
    int tid = threadIdx.x, lane = tid & 63, wid = tid >> 6;
    int base = blockIdx.x * 1024 + tid * 4;
    int v0 = (base + 0 < n) ? cnt[base + 0] : 0;
    int v1 = (base + 1 < n) ? cnt[base + 1] : 0;
    int v2 = (base + 2 < n) ? cnt[base + 2] : 0;
    int v3 = (base + 3 < n) ? cnt[base + 3] : 0;
    if (base + 0 < n) dinv[base + 0] = 1.0f / sqrtf(1.0f + (float)v0);
    if (base + 1 < n) dinv[base + 1] = 1.0f / sqrtf(1.0f + (float)v1);
    if (base + 2 < n) dinv[base + 2] = 1.0f / sqrtf(1.0f + (float)v2);
    if (base + 3 < n) dinv[base + 3] = 1.0f / sqrtf(1.0f + (float)v3);
    int lsum = v0 + v1 + v2 + v3;
    int s = lsum;
#pragma unroll
    for (int off = 1; off < 64; off <<= 1) {
        int t = __shfl_up(s, off);
        if (lane >= off) s += t;
    }
    __shared__ int wt[4];
    if (lane == 63) wt[wid] = s;
    __syncthreads();
    int woff = 0;
    for (int w = 0; w < wid; ++w) woff += wt[w];
    int excl = woff + s - lsum;
    if (base + 0 < n) offs[base + 0] = excl;
    if (base + 1 < n) offs[base + 1] = excl + v0;
    if (base + 2 < n) offs[base + 2] = excl + v0 + v1;
    if (base + 3 < n) offs[base + 3] = excl + v0 + v1 + v2;
    if (tid == 0) bsums[blockIdx.x] = wt[0] + wt[1] + wt[2] + wt[3];
}

// ---- scanC: add block offsets (each block sums bsums[0..b) itself) ----
__global__ __launch_bounds__(256) void scanC_k(int* __restrict__ offs,
                                               const int* __restrict__ bsums,
                                               int n, int nE) {
    int boff = 0;
    for (int b = 0; b < (int)blockIdx.x; ++b) boff += bsums[b];
    int base = blockIdx.x * 1024 + threadIdx.x * 4;
#pragma unroll
    for (int j = 0; j < 4; ++j) {
        int i = base + j;
        if (i < n) offs[i] += boff;
    }
    if (blockIdx.x == 0 && threadIdx.x == 0) offs[n] = nE;
}

// ---- atomic-free CSR fill using captured ranks ----
__global__ void fill_rank_k(const int* __restrict__ src, const int* __restrict__ dst,
                            const int* __restrict__ rank_, const int* __restrict__ offs,
                            int* __restrict__ elist, int nE) {
    int e = blockIdx.x * blockDim.x + threadIdx.x;
    if (e < nE) elist[offs[dst[e]] + rank_[e]] = src[e];
}

// ---- MFMA matmul: per branch (blockIdx.y), Oa = f16(dinv*(X@Wa)),
//      and (NW==2) Oc = f16(X@Wc). One wave = 16-row x 64-col slab.
// 16x16x32 f16 layouts: A[row=l&15][k=(l>>4)*8+j]; B[k=(l>>4)*8+j][col=l&15];
// D[row=(l>>4)*4+j][col=l&15]  (m89-verified C/D mapping).
template <int NW, bool F16IN>
__global__ __launch_bounds__(256) void mm_mfma_k(
    const void* __restrict__ X1, const void* __restrict__ X2,
    const float* __restrict__ Wa1, const float* __restrict__ Wa2,
    const float* __restrict__ Wc1, const float* __restrict__ Wc2,
    const float* __restrict__ dinv,
    f16* __restrict__ Oa1, f16* __restrict__ Oa2,
    f16* __restrict__ Oc1, f16* __restrict__ Oc2,
    int xP, int oP, int n) {
    const int branch = blockIdx.y;
    const void* X   = branch ? X2 : X1;
    const float* Wa = branch ? Wa2 : Wa1;
    const float* Wc = branch ? Wc2 : Wc1;
    f16* Oa = branch ? Oa2 : Oa1;
    f16* Oc = branch ? Oc2 : Oc1;

    const int lane = threadIdx.x & 63;
    const int col = lane & 15;
    const int kgrp = lane >> 4;

    f16x8 wa[4][2], wc[4][2];
#pragma unroll
    for (int ct = 0; ct < 4; ++ct)
#pragma unroll
        for (int kk = 0; kk < 2; ++kk) {
#pragma unroll
            for (int j = 0; j < 8; ++j) {
                int widx = (kk * 32 + kgrp * 8 + j) * 64 + ct * 16 + col;
                wa[ct][kk][j] = (f16)Wa[widx];
                if (NW == 2) wc[ct][kk][j] = (f16)Wc[widx];
            }
        }

    const int wid = blockIdx.x * 4 + (threadIdx.x >> 6);
    const int nwaves = gridDim.x * 4;
    const int ntiles = (n + 15) >> 4;
    for (int t = wid; t < ntiles; t += nwaves) {
        int arow = t * 16 + col;
        if (arow >= n) arow = n - 1;
        f16x8 af[2];
#pragma unroll
        for (int kk = 0; kk < 2; ++kk) {
            if (F16IN) {
                af[kk] = *(const f16x8*)((const f16*)X + (size_t)arow * xP + kk * 32 + kgrp * 8);
            } else {
                const float4* px = (const float4*)((const float*)X + (size_t)arow * xP + kk * 32 + kgrp * 8);
                float4 u0 = px[0], u1 = px[1];
                af[kk][0] = (f16)u0.x; af[kk][1] = (f16)u0.y;
                af[kk][2] = (f16)u0.z; af[kk][3] = (f16)u0.w;
                af[kk][4] = (f16)u1.x; af[kk][5] = (f16)u1.y;
                af[kk][6] = (f16)u1.z; af[kk][7] = (f16)u1.w;
            }
        }
        f32x4 acca[4], accc[4];
#pragma unroll
        for (int ct = 0; ct < 4; ++ct) {
            acca[ct] = (f32x4)(0.0f);
            if (NW == 2) accc[ct] = (f32x4)(0.0f);
        }
#pragma unroll
        for (int ct = 0; ct < 4; ++ct)
#pragma unroll
            for (int kk = 0; kk < 2; ++kk) {
                acca[ct] = __builtin_amdgcn_mfma_f32_16x16x32_f16(af[kk], wa[ct][kk], acca[ct], 0, 0, 0);
                if (NW == 2)
                    accc[ct] = __builtin_amdgcn_mfma_f32_16x16x32_f16(af[kk], wc[ct][kk], accc[ct], 0, 0, 0);
            }
        int rbase = t * 16 + kgrp * 4;
#pragma unroll
        for (int j = 0; j < 4; ++j) {
            int row = rbase + j;
            if (row < n) {
                float d = dinv[row];
#pragma unroll
                for (int ct = 0; ct < 4; ++ct) {
                    Oa[(size_t)row * oP + ct * 16 + col] = (f16)(d * acca[ct][j]);
                    if (NW == 2)
                        Oc[(size_t)row * oP + ct * 16 + col] = (f16)(accc[ct][j]);
                }
            }
        }
    }
}

// ---- layer-1 agg, BOTH branches in one pass over interleaved table ----
__global__ __launch_bounds__(256) void agg1_k(
    const int* __restrict__ offs, const int* __restrict__ elist,
    const uint32_t* __restrict__ Aw, const uint32_t* __restrict__ Sw,
    const float* __restrict__ b1, const float* __restrict__ b1s,
    const float* __restrict__ be, const float* __restrict__ bes,
    const float* __restrict__ dinv, uint32_t* __restrict__ Hw, int n) {
    int node = blockIdx.x * 4 + (threadIdx.x >> 6);
    int lane = threadIdx.x & 63;
    if (node >= n) return;
    int br = lane >> 5;
    int ch0 = (lane & 31) * 2;
    float bb0 = br ? b1s[ch0] : b1[ch0];
    float bb1 = br ? b1s[ch0 + 1] : b1[ch0 + 1];
    float bs0 = br ? bes[ch0] : be[ch0];
    float bs1 = br ? bes[ch0 + 1] : be[ch0 + 1];

    int e0 = offs[node], e1 = offs[node + 1];
    f16x2 selfv = __builtin_bit_cast(f16x2, Aw[(size_t)node * 64 + lane]);
    float acc0 = (float)selfv.x, acc1 = (float)selfv.y;
    int e = e0;
    for (; e + 7 < e1; e += 8) {
        int s0 = elist[e], s1 = elist[e + 1], s2 = elist[e + 2], s3 = elist[e + 3];
        int s4 = elist[e + 4], s5 = elist[e + 5], s6 = elist[e + 6], s7 = elist[e + 7];
        f16x2 v0 = __builtin_bit_cast(f16x2, Aw[(size_t)s0 * 64 + lane]);
        f16x2 v1 = __builtin_bit_cast(f16x2, Aw[(size_t)s1 * 64 + lane]);
        f16x2 v2 = __builtin_bit_cast(f16x2, Aw[(size_t)s2 * 64 + lane]);
        f16x2 v3 = __builtin_bit_cast(f16x2, Aw[(size_t)s3 * 64 + lane]);
        f16x2 v4 = __builtin_bit_cast(f16x2, Aw[(size_t)s4 * 64 + lane]);
        f16x2 v5 = __builtin_bit_cast(f16x2, Aw[(size_t)s5 * 64 + lane]);
        f16x2 v6 = __builtin_bit_cast(f16x2, Aw[(size_t)s6 * 64 + lane]);
        f16x2 v7 = __builtin_bit_cast(f16x2, Aw[(size_t)s7 * 64 + lane]);
        acc0 += (((float)v0.x + (float)v1.x) + ((float)v2.x + (float)v3.x)) +
                (((float)v4.x + (float)v5.x) + ((float)v6.x + (float)v7.x));
        acc1 += (((float)v0.y + (float)v1.y) + ((float)v2.y + (float)v3.y)) +
                (((float)v4.y + (float)v5.y) + ((float)v6.y + (float)v7.y));
    }
    for (; e < e1; ++e) {
        f16x2 v = __builtin_bit_cast(f16x2, Aw[(size_t)elist[e] * 64 + lane]);
        acc0 += (float)v.x;
        acc1 += (float)v.y;
    }
    float d = dinv[node];
    float g0 = fmaxf(d * acc0 + bb0, 0.0f);
    float g1 = fmaxf(d * acc1 + bb1, 0.0f);
    f16x2 sv = __builtin_bit_cast(f16x2, Sw[(size_t)node * 64 + lane]);
    g0 += fmaxf((float)sv.x + bs0, 0.0f);
    g1 += fmaxf((float)sv.y + bs1, 0.0f);
    f16x2 o; o.x = (f16)g0; o.y = (f16)g1;
    Hw[(size_t)node * 64 + lane] = __builtin_bit_cast(uint32_t, o);
}

// ---- layer-2 agg + Wf dot, BOTH branches in one pass ----
__global__ __launch_bounds__(256) void agg2_dot_k(
    const int* __restrict__ offs, const int* __restrict__ elist,
    const uint32_t* __restrict__ Aw, const uint32_t* __restrict__ Hw,
    const float* __restrict__ b2, const float* __restrict__ b2s,
    const float* __restrict__ Wf, const float* __restrict__ dinv,
    float* __restrict__ dot, int n) {
    int node = blockIdx.x * 4 + (threadIdx.x >> 6);
    int lane = threadIdx.x & 63;
    if (node >= n) return;
    int br = lane >> 5;
    int ch0 = (lane & 31) * 2;
    float bb0 = br ? b2s[ch0] : b2[ch0];
    float bb1 = br ? b2s[ch0 + 1] : b2[ch0 + 1];
    float wf0 = Wf[ch0], wf1 = Wf[ch0 + 1];

    int e0 = offs[node], e1 = offs[node + 1];
    f16x2 selfv = __builtin_bit_cast(f16x2, Aw[(size_t)node * 64 + lane]);
    float acc0 = (float)selfv.x, acc1 = (float)selfv.y;
    int e = e0;
    for (; e + 7 < e1; e += 8) {
        int s0 = elist[e], s1 = elist[e + 1], s2 = elist[e + 2], s3 = elist[e + 3];
        int s4 = elist[e + 4], s5 = elist[e + 5], s6 = elist[e + 6], s7 = elist[e + 7];
        f16x2 v0 = __builtin_bit_cast(f16x2, Aw[(size_t)s0 * 64 + lane]);
        f16x2 v1 = __builtin_bit_cast(f16x2, Aw[(size_t)s1 * 64 + lane]);
        f16x2 v2 = __builtin_bit_cast(f16x2, Aw[(size_t)s2 * 64 + lane]);
        f16x2 v3 = __builtin_bit_cast(f16x2, Aw[(size_t)s3 * 64 + lane]);
        f16x2 v4 = __builtin_bit_cast(f16x2, Aw[(size_t)s4 * 64 + lane]);
        f16x2 v5 = __builtin_bit_cast(f16x2, Aw[(size_t)s5 * 64 + lane]);
        f16x2 v6 = __builtin_bit_cast(f16x2, Aw[(size_t)s6 * 64 + lane]);
        f16x2 v7 = __builtin_bit_cast(f16x2, Aw[(size_t)s7 * 64 + lane]);
        acc0 += (((float)v0.x + (float)v1.x) + ((float)v2.x + (float)v3.x)) +
                (((float)v4.x + (float)v5.x) + ((float)v6.x + (float)v7.x));
        acc1 += (((float)v0.y + (float)v1.y) + ((float)v2.y + (float)v3.y)) +
                (((float)v4.y + (float)v5.y) + ((float)v6.y + (float)v7.y));
    }
    for (; e < e1; ++e) {
        f16x2 v = __builtin_bit_cast(f16x2, Aw[(size_t)elist[e] * 64 + lane]);
        acc0 += (float)v.x;
        acc1 += (float)v.y;
    }
    float d = dinv[node];
    f16x2 hv = __builtin_bit_cast(f16x2, Hw[(size_t)node * 64 + lane]);
    float h0 = fmaxf(d * acc0 + bb0, 0.0f) + (float)hv.x;
    float h1 = fmaxf(d * acc1 + bb1, 0.0f) + (float)hv.y;
    float c = h0 * wf0 + h1 * wf1;
#pragma unroll
    for (int off = 32; off > 0; off >>= 1) c += __shfl_down(c, off);
    if (lane == 0) dot[node] = c;
}

// ---- pool: one block per graph over per-node dots (batch sorted) ----
__device__ inline int lower_bound(const int* __restrict__ batch, int n, int g) {
    int lo = 0, hi = n;
    while (lo < hi) {
        int mid = (lo + hi) >> 1;
        if (batch[mid] < g) lo = mid + 1; else hi = mid;
    }
    return lo;
}

__global__ __launch_bounds__(256) void pool_reduce_k(
    const float* __restrict__ dot, const int* __restrict__ batch, int n,
    const float* __restrict__ bf, float* __restrict__ out) {
    int g = blockIdx.x;
    int start = lower_bound(batch, n, g);
    int end = lower_bound(batch, n, g + 1);
    int tid = threadIdx.x, lane = tid & 63, wid = tid >> 6;
    float acc = 0.f;
    for (int i = start + tid; i < end; i += blockDim.x) acc += dot[i];
#pragma unroll
    for (int off = 32; off > 0; off >>= 1) acc += __shfl_down(acc, off);
    __shared__ float part[4];
    if (lane == 0) part[wid] = acc;
    __syncthreads();
    if (tid == 0) {
        float s = part[0] + part[1] + part[2] + part[3];
        float cnt = fmaxf((float)(end - start), 1.0f);
        out[g] = s / cnt + bf[0];
    }
}

static inline char* alignp(char* p, uintptr_t a) {
    return (char*)(((uintptr_t)p + a - 1) & ~(a - 1));
}

extern "C" void kernel_launch(void* const* d_in, const int* in_sizes, int n_in,
                              void* d_out, int out_size, void* d_ws, size_t ws_size,
                              hipStream_t stream) {
    const float* x    = (const float*)d_in[0];
    const float* x_SC = (const float*)d_in[1];
    const float* W1   = (const float*)d_in[2];
    const float* b1   = (const float*)d_in[3];
    const float* W2   = (const float*)d_in[4];
    const float* b2   = (const float*)d_in[5];
    const float* We   = (const float*)d_in[6];
    const float* be   = (const float*)d_in[7];
    const float* W1s  = (const float*)d_in[8];
    const float* b1s  = (const float*)d_in[9];
    const float* W2s  = (const float*)d_in[10];
    const float* b2s  = (const float*)d_in[11];
    const float* Wes  = (const float*)d_in[12];
    const float* bes  = (const float*)d_in[13];
    const float* Wf   = (const float*)d_in[14];
    const float* bf   = (const float*)d_in[15];
    const int* ei     = (const int*)d_in[16];
    const int* batch  = (const int*)d_in[17];

    const int nN = in_sizes[0] / 64;   // 50000
    const int nE = in_sizes[16] / 2;   // 800000
    const int nG = out_size;           // 64
    const int* esrc = ei;
    const int* edst = ei + nE;
    const int nb = (nN + 1023) / 1024;

    // ---- workspace (64B-aligned chunks) ----
    char* p = (char*)d_ws;
    int* cnt    = (int*)p;   p = alignp(p + (size_t)nN * sizeof(int), 64);
    int* rank_  = (int*)p;   p = alignp(p + (size_t)nE * sizeof(int), 64);
    int* offs   = (int*)p;   p = alignp(p + (size_t)(nN + 1) * sizeof(int), 64);
    int* bsums  = (int*)p;   p = alignp(p + 1024 * sizeof(int), 64);
    int* elist  = (int*)p;   p = alignp(p + (size_t)nE * sizeof(int), 64);
    float* dinv = (float*)p; p = alignp(p + (size_t)nN * sizeof(float), 64);
    float* dot  = (float*)p; p = alignp(p + (size_t)nN * sizeof(float), 64);
    f16* A = (f16*)p;        p = alignp(p + (size_t)nN * 128 * sizeof(f16), 64);
    f16* S = (f16*)p;        p = alignp(p + (size_t)nN * 128 * sizeof(f16), 64);
    f16* H = (f16*)p;        p = alignp(p + (size_t)nN * 128 * sizeof(f16), 64);

    const int thr = 256;
    const int gEdgeT = (nE + thr - 1) / thr;   // 3125
    const int gNodeW = (nN + 3) / 4;           // 1 wave/node

    // ---- CSR build: histogram+rank, scan(+dinv), add-offsets, atomic-free fill
    hipMemsetAsync(cnt, 0, (size_t)nN * sizeof(int), stream);
    deg_rank_k<<<gEdgeT, thr, 0, stream>>>(edst, nE, cnt, rank_);
    scanA_k<<<nb, thr, 0, stream>>>(cnt, nN, offs, bsums, dinv);
    scanC_k<<<nb, thr, 0, stream>>>(offs, bsums, nN, nE);
    fill_rank_k<<<gEdgeT, thr, 0, stream>>>(esrc, edst, rank_, offs, elist, nE);

    // ---- layer 1: A[:,0:64]=f16(d*(x@W1)), A[:,64:128]=f16(d*(xsc@W1s)),
    //               S likewise with We/Wes (unscaled) ----
    mm_mfma_k<2, false><<<dim3(256, 2), thr, 0, stream>>>(
        x, x_SC, W1, W1s, We, Wes, dinv,
        A, A + 64, S, S + 64, 64, 128, nN);
    agg1_k<<<gNodeW, thr, 0, stream>>>(offs, elist, (const uint32_t*)A, (const uint32_t*)S,
                                       b1, b1s, be, bes, dinv, (uint32_t*)H, nN);

    // ---- layer 2: A = f16(d*(H@W2)) per branch (interleaved in/out) ----
    mm_mfma_k<1, true><<<dim3(256, 2), thr, 0, stream>>>(
        H, H + 64, W2, W2s, nullptr, nullptr, dinv,
        A, A + 64, nullptr, nullptr, 128, 128, nN);
    agg2_dot_k<<<gNodeW, thr, 0, stream>>>(offs, elist, (const uint32_t*)A, (const uint32_t*)H,
                                           b2, b2s, Wf, dinv, dot, nN);

    // ---- pool ----
    pool_reduce_k<<<nG, thr, 0, stream>>>(dot, batch, nN, bf, (float*)d_out);
}